// Round 7
// baseline (785.089 us; speedup 1.0000x reference)
//
#include <hip/hip_runtime.h>
#include <hip/hip_bf16.h>

// B=512, T=2048, S=16, H=128, A=4.  NTOK = 1,048,576 tokens.
// Transposed MFMA chain, v_mfma_f32_16x16x16f16 (K=16: D layout == B layout,
// so chained GEMMs need no data movement; tokens live in lanes).
// Numerics (verified round 6, absmax 0.0625): the QP-amplified chain
// (z2/sech2/dh/f/G) uses split-f16 (hi+lo, 3 MFMAs/product, ~2^-22 rel err);
// the u_unc chain (z1->ua) has O(1) sensitivity and stays single f16.
// Round-7 structure change: weight A-frags live in LDS (read per use, 58
// ds_read_b64/tile/wave ~= 37us/CU total), NOT persistent VGPRs -- round 6's
// 152 VGPRs gave only 3 waves/SIMD and the serial MFMA->tanh->MFMA chain
// went latency-bound (MfmaUtil 17 / VALUBusy 49 / Occ 11%). Each block packs
// its own LDS from the raw inputs (no pack kernel, no d_ws, one dispatch).
#define HDIM 128
#define SDIM 16
#define ADIM 4
#define NTOK (512 * 2048)
#define NTILE (NTOK / 16)      // 65536 16-token tiles
#define NBLK 2048
#define WPB 4                  // waves per 256-thread block
#define TPW (NTILE / (NBLK * WPB))   // 8 tiles per wave

typedef _Float16 half4 __attribute__((ext_vector_type(4)));
typedef float f32x4 __attribute__((ext_vector_type(4)));

__device__ __forceinline__ f32x4 mm(half4 a, half4 b, f32x4 c) {
    return __builtin_amdgcn_mfma_f32_16x16x16f16(a, b, c, 0, 0, 0);
}
__device__ __forceinline__ float fast_tanh(float x) {
    float e = __expf(2.0f * x);
    return 1.0f - 2.0f * __builtin_amdgcn_rcpf(e + 1.0f);
}
__device__ __forceinline__ f32x4 tanh4(f32x4 z) {
    f32x4 r;
    r.x = fast_tanh(z.x); r.y = fast_tanh(z.y);
    r.z = fast_tanh(z.z); r.w = fast_tanh(z.w);
    return r;
}
__device__ __forceinline__ half4 toh(f32x4 v) {
    half4 h;
    h.x = (_Float16)v.x; h.y = (_Float16)v.y;
    h.z = (_Float16)v.z; h.w = (_Float16)v.w;
    return h;
}
// split fp32 vector into f16 hi + f16 lo (x ~= hi + lo, residual ~2^-22 x)
__device__ __forceinline__ void split4(f32x4 v, half4& hi, half4& lo) {
    hi = toh(v);
    f32x4 r;
    r.x = v.x - (float)hi.x; r.y = v.y - (float)hi.y;
    r.z = v.z - (float)hi.z; r.w = v.w - (float)hi.w;
    lo = toh(r);
}
__device__ __forceinline__ float dot4(f32x4 a, f32x4 b) {
    return a.x*b.x + a.y*b.y + a.z*b.z + a.w*b.w;
}
__device__ __forceinline__ float redq(float v) {   // sum over the 4 lane-quads
    v += __shfl_xor(v, 16, 64);
    v += __shfl_xor(v, 32, 64);
    return v;
}

// __launch_bounds__(256, 5): 5 waves/EU -> VGPR cap 102, 5 blocks/CU;
// LDS 30KB x 5 = 150KB <= 160KB (LDS and VGPR limits balanced on purpose).
__global__ __launch_bounds__(256, 5) void cbf_qp_kernel(
    const float* __restrict__ state,
    const float* __restrict__ Wc1, const float* __restrict__ bc1,
    const float* __restrict__ Wc2, const float* __restrict__ bc2,
    const float* __restrict__ Wh1, const float* __restrict__ bh1,
    const float* __restrict__ wh2, const float* __restrict__ bh2,
    const float* __restrict__ Wf,  const float* __restrict__ bf,
    const float* __restrict__ Wg,  const float* __restrict__ bg,
    float* __restrict__ out)
{
    // ---- LDS weight A-frags: [chunk][lane] half4 --------------------------
    __shared__ half4 az1_s[8 * 64];    // Wc1^T
    __shared__ half4 aua_s[8 * 64];    // Wc2^T (rows >= 4 zero)
    __shared__ half4 az2h_s[8 * 64];   // Wh1^T hi
    __shared__ half4 az2l_s[8 * 64];   // Wh1^T lo
    __shared__ half4 adhh_s[8 * 64];   // (Wh1 .* wh2) hi
    __shared__ half4 adhl_s[8 * 64];   // (Wh1 .* wh2) lo
    __shared__ half4 afh_s[64];        // Wf^T hi
    __shared__ half4 afl_s[64];        // Wf^T lo
    __shared__ half4 agh_s[4 * 64];    // Wg^T permuted hi (chunk a: A[s][k]=Wg[k][s*4+a])
    __shared__ half4 agl_s[4 * 64];    // Wg^T permuted lo
    __shared__ float bgt_s[64];        // bgt[a][s] = bg[s*4+a]

    const int tid = threadIdx.x;

    // ---- per-block pack: raw global weights -> LDS frags ------------------
    // A-frag layout: lane l holds A[m][k], m = l&15, k = (l>>4)*4 + e
    for (int idx = tid; idx < 8 * 64; idx += 256) {
        const int c = idx >> 6, lane = idx & 63;
        const int m = lane & 15, q = lane >> 4;
        half4 hz1, hua, h2h, h2l, hdh, hdl;
        #pragma unroll
        for (int e = 0; e < 4; ++e) {
            const int k = q * 4 + e;
            const int j = c * 16 + k;
            hz1[e] = (_Float16)Wc1[k * HDIM + c*16 + m];
            hua[e] = (m < ADIM) ? (_Float16)Wc2[j * ADIM + m] : (_Float16)0.f;
            float w2 = Wh1[k * HDIM + c*16 + m];
            _Float16 hh = (_Float16)w2;
            h2h[e] = hh; h2l[e] = (_Float16)(w2 - (float)hh);
            float wd = Wh1[m * HDIM + j] * wh2[j];
            _Float16 hd = (_Float16)wd;
            hdh[e] = hd; hdl[e] = (_Float16)(wd - (float)hd);
        }
        az1_s[idx] = hz1;  aua_s[idx] = hua;
        az2h_s[idx] = h2h; az2l_s[idx] = h2l;
        adhh_s[idx] = hdh; adhl_s[idx] = hdl;
    }
    if (tid < 64) {                                  // Wf^T split
        const int m = tid & 15, q = tid >> 4;
        half4 fh, fl;
        #pragma unroll
        for (int e = 0; e < 4; ++e) {
            float w = Wf[(q*4+e) * SDIM + m];
            _Float16 h = (_Float16)w;
            fh[e] = h; fl[e] = (_Float16)(w - (float)h);
        }
        afh_s[tid] = fh; afl_s[tid] = fl;
    }
    {                                                // Wg^T row-permuted split
        const int a = tid >> 6, lane = tid & 63;
        const int m = lane & 15, q = lane >> 4;      // m = s index
        half4 gh, gl;
        #pragma unroll
        for (int e = 0; e < 4; ++e) {
            float w = Wg[(q*4+e) * 64 + m*4 + a];
            _Float16 h = (_Float16)w;
            gh[e] = h; gl[e] = (_Float16)(w - (float)h);
        }
        agh_s[tid] = gh; agl_s[tid] = gl;
    }
    if (tid < 64)                                    // bgt[a][s] = bg[s*4+a]
        bgt_s[(tid >> 4) * 16 + (tid & 15)] = bg[(tid & 15) * 4 + (tid >> 4)];
    __syncthreads();

    // ---- main: 8 16-token tiles per wave ----------------------------------
    const int lane = tid & 63;
    const int q = lane >> 4, n = lane & 15;
    const int wid = blockIdx.x * WPB + (tid >> 6);

    // small bias C-init frags (L1-resident loads, cheap to keep live)
    f32x4 bfC = *(const f32x4*)(bf + q*4);
    f32x4 uaC;
    {
        f32x4 b2 = *(const f32x4*)(bc2);
        uaC.x = q == 0 ? b2.x : 0.f; uaC.y = q == 0 ? b2.y : 0.f;
        uaC.z = q == 0 ? b2.z : 0.f; uaC.w = q == 0 ? b2.w : 0.f;
    }
    f32x4 bgC0 = *(const f32x4*)(&bgt_s[0*16 + q*4]);
    f32x4 bgC1 = *(const f32x4*)(&bgt_s[1*16 + q*4]);
    f32x4 bgC2 = *(const f32x4*)(&bgt_s[2*16 + q*4]);
    f32x4 bgC3 = *(const f32x4*)(&bgt_s[3*16 + q*4]);
    const float bh2v = bh2[0];

    for (int it = 0; it < TPW; ++it) {
        const int tile = wid * TPW + it;
        // B-frag of state^T: lane(q,n) holds state[token n][q*4 .. q*4+3]
        f32x4 sv = *(const f32x4*)(state + (size_t)(tile*16 + n) * SDIM + q*4);
        half4 bsh, bsl;
        split4(sv, bsh, bsl);

        f32x4 ua = uaC;                    // ua^T accum (rows 0-3 = a)
        f32x4 dh = {0.f, 0.f, 0.f, 0.f};   // dh^T accum (rows = s)
        float hp = 0.f;                    // h partial (reduced over q later)
        #pragma unroll
        for (int c = 0; c < 8; ++c) {
            // ---- low-precision chain: z1 -> tanh -> ua (O(1) sensitivity)
            f32x4 b1 = *(const f32x4*)(bc1 + c*16 + q*4);
            f32x4 z1 = mm(az1_s[c*64 + lane], bsh, b1);
            half4 t1h = toh(tanh4(z1));
            ua = mm(aua_s[c*64 + lane], t1h, ua);

            // ---- high-precision chain: z2 (split x split, 3 MFMAs)
            f32x4 b2v = *(const f32x4*)(bh1 + c*16 + q*4);
            half4 a2h = az2h_s[c*64 + lane];
            f32x4 z2 = mm(a2h, bsl, b2v);
            z2 = mm(az2l_s[c*64 + lane], bsh, z2);
            z2 = mm(a2h, bsh, z2);
            f32x4 t2 = tanh4(z2);
            f32x4 s2;
            s2.x = 1.f - t2.x*t2.x; s2.y = 1.f - t2.y*t2.y;
            s2.z = 1.f - t2.z*t2.z; s2.w = 1.f - t2.w*t2.w;
            half4 s2h, s2l;
            split4(s2, s2h, s2l);
            half4 adh_h = adhh_s[c*64 + lane];
            dh = mm(adh_h, s2l, dh);
            dh = mm(adhl_s[c*64 + lane], s2h, dh);
            dh = mm(adh_h, s2h, dh);

            f32x4 wv = *(const f32x4*)(wh2 + c*16 + q*4);
            hp += dot4(wv, t2);
        }
        // f^T (rows = s) and G chunks (chunk a: row s = g[s][a]) — split path
        half4 fh = afh_s[lane], fl = afl_s[lane];
        f32x4 fD = mm(fh, bsl, bfC);
        fD = mm(fl, bsh, fD);
        fD = mm(fh, bsh, fD);
        f32x4 G0, G1, G2, G3;
        {
            half4 gh = agh_s[0*64 + lane], gl = agl_s[0*64 + lane];
            G0 = mm(gh, bsl, bgC0); G0 = mm(gl, bsh, G0); G0 = mm(gh, bsh, G0);
        }
        {
            half4 gh = agh_s[1*64 + lane], gl = agl_s[1*64 + lane];
            G1 = mm(gh, bsl, bgC1); G1 = mm(gl, bsh, G1); G1 = mm(gh, bsh, G1);
        }
        {
            half4 gh = agh_s[2*64 + lane], gl = agl_s[2*64 + lane];
            G2 = mm(gh, bsl, bgC2); G2 = mm(gl, bsh, G2); G2 = mm(gh, bsh, G2);
        }
        {
            half4 gh = agh_s[3*64 + lane], gl = agl_s[3*64 + lane];
            G3 = mm(gh, bsl, bgC3); G3 = mm(gl, bsh, G3); G3 = mm(gh, bsh, G3);
        }

        // right = h + bh2 + dh.f   (partials live in lane-quads; reduce)
        float right = redq(hp + dot4(dh, fD)) + bh2v;
        float l0 = -redq(dot4(dh, G0));
        float l1 = -redq(dot4(dh, G1));
        float l2 = -redq(dot4(dh, G2));
        float l3 = -redq(dot4(dh, G3));
        // ua rows >= 4 are zero, so quad-reduce == broadcast of rows 0-3
        float u0 = 2.f * redq(ua.x);
        float u1 = 2.f * redq(ua.y);
        float u2 = 2.f * redq(ua.z);
        float u3 = 2.f * redq(ua.w);

        float viol = l0*u0 + l1*u1 + l2*u2 + l3*u3 - right;
        float lsq  = l0*l0 + l1*l1 + l2*l2 + l3*l3;
        float lam  = viol > 0.f ? viol / (lsq + 1e-8f) : 0.f;

        if (q == 0) {                      // lanes 0-15 store their token
            f32x4 uo;
            uo.x = u0 - lam*l0; uo.y = u1 - lam*l1;
            uo.z = u2 - lam*l2; uo.w = u3 - lam*l3;
            *(f32x4*)(out + (size_t)(tile*16 + n) * ADIM) = uo;
        }
    }
}

extern "C" void kernel_launch(void* const* d_in, const int* in_sizes, int n_in,
                              void* d_out, int out_size, void* d_ws, size_t ws_size,
                              hipStream_t stream) {
    (void)in_sizes; (void)n_in; (void)d_ws; (void)ws_size; (void)out_size;
    const float* state = (const float*)d_in[0];
    const float* Wc1   = (const float*)d_in[1];
    const float* bc1   = (const float*)d_in[2];
    const float* Wc2   = (const float*)d_in[3];
    const float* bc2   = (const float*)d_in[4];
    const float* Wh1   = (const float*)d_in[5];
    const float* bh1   = (const float*)d_in[6];
    const float* wh2   = (const float*)d_in[7];
    const float* bh2   = (const float*)d_in[8];
    const float* Wf    = (const float*)d_in[9];
    const float* bf    = (const float*)d_in[10];
    const float* Wg    = (const float*)d_in[11];
    const float* bg    = (const float*)d_in[12];
    float* out = (float*)d_out;

    hipLaunchKernelGGL(cbf_qp_kernel, dim3(NBLK), dim3(256), 0, stream,
                       state, Wc1, bc1, Wc2, bc2, Wh1, bh1, wh2, bh2,
                       Wf, bf, Wg, bg, out);
}

// Round 8
// 286.369 us; speedup vs baseline: 2.7415x; 2.7415x over previous
//
#include <hip/hip_runtime.h>
#include <hip/hip_bf16.h>

// B=512, T=2048, S=16, H=128, A=4.  NTOK = 1,048,576 tokens.
// Transposed MFMA chain, v_mfma_f32_16x16x16f16 (K=16: D layout == B layout,
// so chained GEMMs need no data movement; tokens live in lanes).
// Numerics (verified round 6, absmax 0.0625): QP-amplified chain
// (z2/sech2/dh/f/G) in split-f16 (hi+lo, 3 MFMAs/product); u_unc chain
// (z1->ua) single f16 (O(1) sensitivity).
// Round-8: round-6 latency-bound (MfmaUtil 17/VALU 49/Occ 11, 24-deep dh
// MFMA dependency chain). Fix = split accumulators: dh -> 3 (one per split
// term, 8-deep each), ua -> 2, hp -> 2. +13 VGPR, still 3 waves/SIMD.
// NO launch_bounds cap (round 7: cap 102 -> LLVM spilled loop-invariants,
// 2.25 GB scratch traffic, 785 us). NO LDS weights, NO register batching
// (rounds 1/2 post-mortems).
#define HDIM 128
#define SDIM 16
#define ADIM 4
#define NTOK (512 * 2048)
#define NTILE (NTOK / 16)      // 65536 16-token tiles
#define NBLK 2048
#define WPB 4
#define NWAVE (NBLK * WPB)     // 8192 waves
#define TPW (NTILE / NWAVE)    // 8 tiles per wave

// d_ws byte offsets: half4 A-frags [chunk][lane] (8 B/entry)
#define AZ1   0                // Wc1^T hi          8 chunks (low-prec path)
#define AUA   4096             // Wc2^T hi          8 chunks (rows>=4 zero)
#define AZ2H  8192             // Wh1^T hi          8 chunks
#define AZ2L  12288            // Wh1^T lo
#define ADHH  16384            // (Wh1 .* wh2) hi   8 chunks
#define ADHL  20480            // (Wh1 .* wh2) lo
#define AFH   24576            // Wf^T hi           1 chunk
#define AFL   25088            // Wf^T lo
#define AGH   25600            // Wg^T permuted hi  4 chunks (chunk a: A[s][k]=Wg[k][s*4+a])
#define AGL   27648            // Wg^T permuted lo
#define BGT   29696            // bgt[a][s] = bg[s*4+a]  (64 floats)

typedef _Float16 half4 __attribute__((ext_vector_type(4)));
typedef float f32x4 __attribute__((ext_vector_type(4)));

__device__ __forceinline__ f32x4 mm(half4 a, half4 b, f32x4 c) {
    return __builtin_amdgcn_mfma_f32_16x16x16f16(a, b, c, 0, 0, 0);
}
__device__ __forceinline__ float fast_tanh(float x) {
    float e = __expf(2.0f * x);
    return 1.0f - 2.0f * __builtin_amdgcn_rcpf(e + 1.0f);
}
__device__ __forceinline__ f32x4 tanh4(f32x4 z) {
    f32x4 r;
    r.x = fast_tanh(z.x); r.y = fast_tanh(z.y);
    r.z = fast_tanh(z.z); r.w = fast_tanh(z.w);
    return r;
}
__device__ __forceinline__ half4 toh(f32x4 v) {
    half4 h;
    h.x = (_Float16)v.x; h.y = (_Float16)v.y;
    h.z = (_Float16)v.z; h.w = (_Float16)v.w;
    return h;
}
// split fp32 vector into f16 hi + f16 lo (x ~= hi + lo, residual ~2^-22 x)
__device__ __forceinline__ void split4(f32x4 v, half4& hi, half4& lo) {
    hi = toh(v);
    f32x4 r;
    r.x = v.x - (float)hi.x; r.y = v.y - (float)hi.y;
    r.z = v.z - (float)hi.z; r.w = v.w - (float)hi.w;
    lo = toh(r);
}
__device__ __forceinline__ float dot4(f32x4 a, f32x4 b) {
    return a.x*b.x + a.y*b.y + a.z*b.z + a.w*b.w;
}
__device__ __forceinline__ float redq(float v) {   // sum over the 4 lane-quads
    v += __shfl_xor(v, 16, 64);
    v += __shfl_xor(v, 32, 64);
    return v;
}

__global__ __launch_bounds__(256) void pack_kernel(
    const float* __restrict__ Wc1, const float* __restrict__ Wc2,
    const float* __restrict__ Wh1, const float* __restrict__ wh2,
    const float* __restrict__ Wf,  const float* __restrict__ Wg,
    const float* __restrict__ bg,  char* __restrict__ wsb)
{
    _Float16* az1  = (_Float16*)(wsb + AZ1);
    _Float16* aua  = (_Float16*)(wsb + AUA);
    _Float16* az2h = (_Float16*)(wsb + AZ2H);
    _Float16* az2l = (_Float16*)(wsb + AZ2L);
    _Float16* adhh = (_Float16*)(wsb + ADHH);
    _Float16* adhl = (_Float16*)(wsb + ADHL);
    _Float16* afh  = (_Float16*)(wsb + AFH);
    _Float16* afl  = (_Float16*)(wsb + AFL);
    _Float16* agh  = (_Float16*)(wsb + AGH);
    _Float16* agl  = (_Float16*)(wsb + AGL);
    float*    bgt  = (float*)(wsb + BGT);
    const int tid = threadIdx.x;

    // A-frag layout: lane l holds A[m][k], m = l&15, k = (l>>4)*4 + e
    for (int idx = tid; idx < 8 * 64; idx += 256) {
        const int c = idx >> 6, lane = idx & 63;
        const int m = lane & 15, q = lane >> 4;
        #pragma unroll
        for (int e = 0; e < 4; ++e) {
            const int k = q * 4 + e;        // K index within chunk
            const int j = c * 16 + k;       // global hidden index (for ua/dh)
            az1[idx*4+e] = (_Float16)Wc1[k * HDIM + c*16 + m];
            aua[idx*4+e] = (m < ADIM) ? (_Float16)Wc2[j * ADIM + m] : (_Float16)0.f;
            {   // Wh1^T split
                float w = Wh1[k * HDIM + c*16 + m];
                _Float16 h = (_Float16)w;
                az2h[idx*4+e] = h;
                az2l[idx*4+e] = (_Float16)(w - (float)h);
            }
            {   // (Wh1 .* wh2) split  (A[m=s][k]: row s, col j)
                float w = Wh1[m * HDIM + j] * wh2[j];
                _Float16 h = (_Float16)w;
                adhh[idx*4+e] = h;
                adhl[idx*4+e] = (_Float16)(w - (float)h);
            }
        }
    }
    if (tid < 64) {                                  // Wf^T split
        const int m = tid & 15, q = tid >> 4;
        #pragma unroll
        for (int e = 0; e < 4; ++e) {
            float w = Wf[(q*4+e) * SDIM + m];
            _Float16 h = (_Float16)w;
            afh[tid*4+e] = h;
            afl[tid*4+e] = (_Float16)(w - (float)h);
        }
    }
    for (int idx = tid; idx < 4 * 64; idx += 256) {  // Wg^T row-permuted split
        const int a = idx >> 6, lane = idx & 63;
        const int m = lane & 15, q = lane >> 4;      // m = s index
        #pragma unroll
        for (int e = 0; e < 4; ++e) {
            float w = Wg[(q*4+e) * 64 + m*4 + a];
            _Float16 h = (_Float16)w;
            agh[idx*4+e] = h;
            agl[idx*4+e] = (_Float16)(w - (float)h);
        }
    }
    if (tid < 64) {                                  // bgt[a][s] = bg[s*4+a]
        const int a = tid >> 4, s = tid & 15;
        bgt[a*16 + s] = bg[s*4 + a];
    }
}

__global__ __launch_bounds__(256) void cbf_qp_kernel(
    const float* __restrict__ state,
    const float* __restrict__ bc1, const float* __restrict__ bc2,
    const float* __restrict__ bh1, const float* __restrict__ wh2,
    const float* __restrict__ bh2, const float* __restrict__ bf,
    const char* __restrict__ wsb,  float* __restrict__ out)
{
    const int tid  = threadIdx.x;
    const int lane = tid & 63;
    const int q = lane >> 4, n = lane & 15;
    const int wid = blockIdx.x * WPB + (tid >> 6);

    // ---- persistent per-lane weight A-frags (loaded once, reused 8 tiles) ----
    const half4* pz1  = (const half4*)(wsb + AZ1);
    const half4* pua  = (const half4*)(wsb + AUA);
    const half4* pz2h = (const half4*)(wsb + AZ2H);
    const half4* pz2l = (const half4*)(wsb + AZ2L);
    const half4* pdhh = (const half4*)(wsb + ADHH);
    const half4* pdhl = (const half4*)(wsb + ADHL);
    half4 az1[8], aua[8], az2h[8], az2l[8], adhh[8], adhl[8];
    #pragma unroll
    for (int c = 0; c < 8; ++c) {
        az1[c]  = pz1[c*64 + lane];
        aua[c]  = pua[c*64 + lane];
        az2h[c] = pz2h[c*64 + lane];
        az2l[c] = pz2l[c*64 + lane];
        adhh[c] = pdhh[c*64 + lane];
        adhl[c] = pdhl[c*64 + lane];
    }
    half4 afh = ((const half4*)(wsb + AFH))[lane];
    half4 afl = ((const half4*)(wsb + AFL))[lane];
    half4 agh[4], agl[4];
    #pragma unroll
    for (int a = 0; a < 4; ++a) {
        agh[a] = ((const half4*)(wsb + AGH))[a*64 + lane];
        agl[a] = ((const half4*)(wsb + AGL))[a*64 + lane];
    }

    // C-init frags (biases; broadcast over tokens since D rows are the M axis)
    f32x4 bfC = *(const f32x4*)(bf + q*4);
    f32x4 uaC;
    {
        f32x4 b2 = *(const f32x4*)(bc2);
        uaC.x = q == 0 ? b2.x : 0.f; uaC.y = q == 0 ? b2.y : 0.f;
        uaC.z = q == 0 ? b2.z : 0.f; uaC.w = q == 0 ? b2.w : 0.f;
    }
    const float* bgt = (const float*)(wsb + BGT);
    f32x4 bgC0 = *(const f32x4*)(bgt + 0*16 + q*4);
    f32x4 bgC1 = *(const f32x4*)(bgt + 1*16 + q*4);
    f32x4 bgC2 = *(const f32x4*)(bgt + 2*16 + q*4);
    f32x4 bgC3 = *(const f32x4*)(bgt + 3*16 + q*4);
    const float bh2v = bh2[0];

    for (int it = 0; it < TPW; ++it) {
        const int tile = wid * TPW + it;
        // B-frag of state^T: lane(q,n) holds state[token n][q*4 .. q*4+3]
        f32x4 sv = *(const f32x4*)(state + (size_t)(tile*16 + n) * SDIM + q*4);
        half4 bsh, bsl;
        split4(sv, bsh, bsl);

        // Split accumulators: break the 24-deep dh MFMA dependency chain
        // into three 8-deep chains (and ua into two 4-deep ones).
        f32x4 uaA = uaC, uaB = {0.f, 0.f, 0.f, 0.f};
        f32x4 dhA = {0.f, 0.f, 0.f, 0.f};
        f32x4 dhB = {0.f, 0.f, 0.f, 0.f};
        f32x4 dhC = {0.f, 0.f, 0.f, 0.f};
        float hp0 = 0.f, hp1 = 0.f;
        #pragma unroll
        for (int c = 0; c < 8; ++c) {
            // ---- low-precision chain: z1 -> tanh -> ua (O(1) sensitivity)
            f32x4 b1 = *(const f32x4*)(bc1 + c*16 + q*4);
            f32x4 z1 = mm(az1[c], bsh, b1);
            half4 t1h = toh(tanh4(z1));
            if (c & 1) uaB = mm(aua[c], t1h, uaB);
            else       uaA = mm(aua[c], t1h, uaA);

            // ---- high-precision chain: z2 (split x split, 3 MFMAs)
            f32x4 b2v = *(const f32x4*)(bh1 + c*16 + q*4);
            f32x4 z2 = mm(az2h[c], bsl, b2v);
            z2 = mm(az2l[c], bsh, z2);
            z2 = mm(az2h[c], bsh, z2);
            f32x4 t2 = tanh4(z2);
            f32x4 s2;
            s2.x = 1.f - t2.x*t2.x; s2.y = 1.f - t2.y*t2.y;
            s2.z = 1.f - t2.z*t2.z; s2.w = 1.f - t2.w*t2.w;
            half4 s2h, s2l;
            split4(s2, s2h, s2l);
            dhA = mm(adhh[c], s2h, dhA);   // three independent accumulators:
            dhB = mm(adhl[c], s2h, dhB);   // issue back-to-back, chains overlap
            dhC = mm(adhh[c], s2l, dhC);

            f32x4 wv = *(const f32x4*)(wh2 + c*16 + q*4);
            if (c & 1) hp1 += dot4(wv, t2);
            else       hp0 += dot4(wv, t2);
        }
        f32x4 ua = uaA + uaB;
        f32x4 dh = dhA + dhB + dhC;
        float hp = hp0 + hp1;

        // f^T (rows = s) and G chunks (chunk a: row s = g[s][a]) — split path
        f32x4 fD = mm(afh, bsl, bfC);
        fD = mm(afl, bsh, fD);
        fD = mm(afh, bsh, fD);
        f32x4 G0 = mm(agh[0], bsl, bgC0); G0 = mm(agl[0], bsh, G0); G0 = mm(agh[0], bsh, G0);
        f32x4 G1 = mm(agh[1], bsl, bgC1); G1 = mm(agl[1], bsh, G1); G1 = mm(agh[1], bsh, G1);
        f32x4 G2 = mm(agh[2], bsl, bgC2); G2 = mm(agl[2], bsh, G2); G2 = mm(agh[2], bsh, G2);
        f32x4 G3 = mm(agh[3], bsl, bgC3); G3 = mm(agl[3], bsh, G3); G3 = mm(agh[3], bsh, G3);

        // right = h + bh2 + dh.f   (partials live in lane-quads; reduce)
        float right = redq(hp + dot4(dh, fD)) + bh2v;
        float l0 = -redq(dot4(dh, G0));
        float l1 = -redq(dot4(dh, G1));
        float l2 = -redq(dot4(dh, G2));
        float l3 = -redq(dot4(dh, G3));
        // ua rows >= 4 are zero, so quad-reduce == broadcast of rows 0-3
        float u0 = 2.f * redq(ua.x);
        float u1 = 2.f * redq(ua.y);
        float u2 = 2.f * redq(ua.z);
        float u3 = 2.f * redq(ua.w);

        float viol = l0*u0 + l1*u1 + l2*u2 + l3*u3 - right;
        float lsq  = l0*l0 + l1*l1 + l2*l2 + l3*l3;
        float lam  = viol > 0.f ? viol / (lsq + 1e-8f) : 0.f;

        if (q == 0) {                      // lanes 0-15 store their token
            f32x4 uo;
            uo.x = u0 - lam*l0; uo.y = u1 - lam*l1;
            uo.z = u2 - lam*l2; uo.w = u3 - lam*l3;
            *(f32x4*)(out + (size_t)(tile*16 + n) * ADIM) = uo;
        }
    }
}

extern "C" void kernel_launch(void* const* d_in, const int* in_sizes, int n_in,
                              void* d_out, int out_size, void* d_ws, size_t ws_size,
                              hipStream_t stream) {
    (void)in_sizes; (void)n_in; (void)ws_size; (void)out_size;
    const float* state = (const float*)d_in[0];
    const float* Wc1   = (const float*)d_in[1];
    const float* bc1   = (const float*)d_in[2];
    const float* Wc2   = (const float*)d_in[3];
    const float* bc2   = (const float*)d_in[4];
    const float* Wh1   = (const float*)d_in[5];
    const float* bh1   = (const float*)d_in[6];
    const float* wh2   = (const float*)d_in[7];
    const float* bh2   = (const float*)d_in[8];
    const float* Wf    = (const float*)d_in[9];
    const float* bf    = (const float*)d_in[10];
    const float* Wg    = (const float*)d_in[11];
    const float* bg    = (const float*)d_in[12];
    float* out = (float*)d_out;

    hipLaunchKernelGGL(pack_kernel, dim3(1), dim3(256), 0, stream,
                       Wc1, Wc2, Wh1, wh2, Wf, Wg, bg, (char*)d_ws);
    hipLaunchKernelGGL(cbf_qp_kernel, dim3(NBLK), dim3(256), 0, stream,
                       state, bc1, bc2, bh1, wh2, bh2, bf,
                       (const char*)d_ws, out);
}

// Round 9
// 224.789 us; speedup vs baseline: 3.4926x; 1.2739x over previous
//
#include <hip/hip_runtime.h>
#include <hip/hip_bf16.h>

// B=512, T=2048, S=16, H=128, A=4.  NTOK = 1,048,576 tokens.
// Transposed MFMA chain, v_mfma_f32_16x16x16f16 (K=16: D layout == B layout,
// so chained GEMMs need no data movement; tokens live in lanes).
// Numerics (verified rounds 6/8, absmax 0.0625): QP-amplified chain
// (z2/sech2/dh/f/G) in split-f16 (hi+lo, 3 MFMAs/product); u_unc chain
// (z1->ua) single f16 (O(1) sensitivity).
// Round-9 structure: weights + biases in LDS (~31.5 KB -> 5 blocks/CU),
// in-block pack (single dispatch), split accumulators (round 8),
// __launch_bounds__(256,4) = cap 128, ~30 above live-estimate.
// History: r6/r8 persistent-VGPR weights -> 156 VGPR, 3 waves/SIMD,
// latency-bound at ~198us (MfmaUtil 18/VALU 53/Occ 11). r7 LDS weights with
// cap 102 -> loop-invariant spill, 2.25 GB scratch, 785us. This round keeps
// LDS weights but caps gently; spill signal = hbm_bytes >> 60 MB.
#define HDIM 128
#define SDIM 16
#define ADIM 4
#define NTOK (512 * 2048)
#define NTILE (NTOK / 16)      // 65536 16-token tiles
#define NBLK 2048
#define WPB 4                  // waves per 256-thread block
#define TPW (NTILE / (NBLK * WPB))   // 8 tiles per wave

typedef _Float16 half4 __attribute__((ext_vector_type(4)));
typedef float f32x4 __attribute__((ext_vector_type(4)));

__device__ __forceinline__ f32x4 mm(half4 a, half4 b, f32x4 c) {
    return __builtin_amdgcn_mfma_f32_16x16x16f16(a, b, c, 0, 0, 0);
}
__device__ __forceinline__ float fast_tanh(float x) {
    float e = __expf(2.0f * x);
    return 1.0f - 2.0f * __builtin_amdgcn_rcpf(e + 1.0f);
}
__device__ __forceinline__ f32x4 tanh4(f32x4 z) {
    f32x4 r;
    r.x = fast_tanh(z.x); r.y = fast_tanh(z.y);
    r.z = fast_tanh(z.z); r.w = fast_tanh(z.w);
    return r;
}
__device__ __forceinline__ half4 toh(f32x4 v) {
    half4 h;
    h.x = (_Float16)v.x; h.y = (_Float16)v.y;
    h.z = (_Float16)v.z; h.w = (_Float16)v.w;
    return h;
}
// split fp32 vector into f16 hi + f16 lo (x ~= hi + lo, residual ~2^-22 x)
__device__ __forceinline__ void split4(f32x4 v, half4& hi, half4& lo) {
    hi = toh(v);
    f32x4 r;
    r.x = v.x - (float)hi.x; r.y = v.y - (float)hi.y;
    r.z = v.z - (float)hi.z; r.w = v.w - (float)hi.w;
    lo = toh(r);
}
__device__ __forceinline__ float dot4(f32x4 a, f32x4 b) {
    return a.x*b.x + a.y*b.y + a.z*b.z + a.w*b.w;
}
__device__ __forceinline__ float redq(float v) {   // sum over the 4 lane-quads
    v += __shfl_xor(v, 16, 64);
    v += __shfl_xor(v, 32, 64);
    return v;
}

__global__ __launch_bounds__(256, 4) void cbf_qp_kernel(
    const float* __restrict__ state,
    const float* __restrict__ Wc1, const float* __restrict__ bc1,
    const float* __restrict__ Wc2, const float* __restrict__ bc2,
    const float* __restrict__ Wh1, const float* __restrict__ bh1,
    const float* __restrict__ wh2, const float* __restrict__ bh2,
    const float* __restrict__ Wf,  const float* __restrict__ bf,
    const float* __restrict__ Wg,  const float* __restrict__ bg,
    float* __restrict__ out)
{
    // ---- LDS weight A-frags: [chunk][lane] half4 --------------------------
    __shared__ __align__(16) half4 az1_s[8 * 64];    // Wc1^T
    __shared__ __align__(16) half4 aua_s[8 * 64];    // Wc2^T (rows >= 4 zero)
    __shared__ __align__(16) half4 az2h_s[8 * 64];   // Wh1^T hi
    __shared__ __align__(16) half4 az2l_s[8 * 64];   // Wh1^T lo
    __shared__ __align__(16) half4 adhh_s[8 * 64];   // (Wh1 .* wh2) hi
    __shared__ __align__(16) half4 adhl_s[8 * 64];   // (Wh1 .* wh2) lo
    __shared__ __align__(16) half4 afh_s[64];        // Wf^T hi
    __shared__ __align__(16) half4 afl_s[64];        // Wf^T lo
    __shared__ __align__(16) half4 agh_s[4 * 64];    // Wg^T permuted hi (chunk a: A[s][k]=Wg[k][s*4+a])
    __shared__ __align__(16) half4 agl_s[4 * 64];    // Wg^T permuted lo
    __shared__ __align__(16) float bgt_s[64];        // bgt[a][s] = bg[s*4+a]
    __shared__ __align__(16) float bc1_s[HDIM];      // biases staged to LDS so the
    __shared__ __align__(16) float bh1_s[HDIM];      // allocator can't hoist 96 regs
    __shared__ __align__(16) float wh2_s[HDIM];      // of loop-invariant loads (r6)

    const int tid = threadIdx.x;

    // ---- per-block pack: raw global weights -> LDS frags ------------------
    // A-frag layout: lane l holds A[m][k], m = l&15, k = (l>>4)*4 + e
    for (int idx = tid; idx < 8 * 64; idx += 256) {
        const int c = idx >> 6, lane = idx & 63;
        const int m = lane & 15, q = lane >> 4;
        half4 hz1, hua, h2h, h2l, hdh, hdl;
        #pragma unroll
        for (int e = 0; e < 4; ++e) {
            const int k = q * 4 + e;
            const int j = c * 16 + k;
            hz1[e] = (_Float16)Wc1[k * HDIM + c*16 + m];
            hua[e] = (m < ADIM) ? (_Float16)Wc2[j * ADIM + m] : (_Float16)0.f;
            float w2 = Wh1[k * HDIM + c*16 + m];
            _Float16 hh = (_Float16)w2;
            h2h[e] = hh; h2l[e] = (_Float16)(w2 - (float)hh);
            float wd = Wh1[m * HDIM + j] * wh2[j];
            _Float16 hd = (_Float16)wd;
            hdh[e] = hd; hdl[e] = (_Float16)(wd - (float)hd);
        }
        az1_s[idx] = hz1;  aua_s[idx] = hua;
        az2h_s[idx] = h2h; az2l_s[idx] = h2l;
        adhh_s[idx] = hdh; adhl_s[idx] = hdl;
    }
    if (tid < 64) {                                  // Wf^T split
        const int m = tid & 15, q = tid >> 4;
        half4 fh, fl;
        #pragma unroll
        for (int e = 0; e < 4; ++e) {
            float w = Wf[(q*4+e) * SDIM + m];
            _Float16 h = (_Float16)w;
            fh[e] = h; fl[e] = (_Float16)(w - (float)h);
        }
        afh_s[tid] = fh; afl_s[tid] = fl;
    }
    {                                                // Wg^T row-permuted split
        const int a = tid >> 6, lane = tid & 63;
        const int m = lane & 15, q = lane >> 4;      // m = s index
        half4 gh, gl;
        #pragma unroll
        for (int e = 0; e < 4; ++e) {
            float w = Wg[(q*4+e) * 64 + m*4 + a];
            _Float16 h = (_Float16)w;
            gh[e] = h; gl[e] = (_Float16)(w - (float)h);
        }
        agh_s[tid] = gh; agl_s[tid] = gl;
    }
    if (tid < 64)                                    // bgt[a][s] = bg[s*4+a]
        bgt_s[(tid >> 4) * 16 + (tid & 15)] = bg[(tid & 15) * 4 + (tid >> 4)];
    if (tid < HDIM) {
        bc1_s[tid] = bc1[tid];
        bh1_s[tid] = bh1[tid];
        wh2_s[tid] = wh2[tid];
    }
    __syncthreads();

    // ---- main: 8 16-token tiles per wave ----------------------------------
    const int lane = tid & 63;
    const int q = lane >> 4, n = lane & 15;
    const int wid = blockIdx.x * WPB + (tid >> 6);

    f32x4 bfC = *(const f32x4*)(bf + q*4);
    f32x4 uaC;
    {
        f32x4 b2 = *(const f32x4*)(bc2);
        uaC.x = q == 0 ? b2.x : 0.f; uaC.y = q == 0 ? b2.y : 0.f;
        uaC.z = q == 0 ? b2.z : 0.f; uaC.w = q == 0 ? b2.w : 0.f;
    }
    f32x4 bgC0 = *(const f32x4*)(&bgt_s[0*16 + q*4]);
    f32x4 bgC1 = *(const f32x4*)(&bgt_s[1*16 + q*4]);
    f32x4 bgC2 = *(const f32x4*)(&bgt_s[2*16 + q*4]);
    f32x4 bgC3 = *(const f32x4*)(&bgt_s[3*16 + q*4]);
    const float bh2v = bh2[0];

    for (int it = 0; it < TPW; ++it) {
        const int tile = wid * TPW + it;
        // B-frag of state^T: lane(q,n) holds state[token n][q*4 .. q*4+3]
        f32x4 sv = *(const f32x4*)(state + (size_t)(tile*16 + n) * SDIM + q*4);
        half4 bsh, bsl;
        split4(sv, bsh, bsl);

        // Split accumulators (r8): dh 3x 8-deep chains, ua 2x, hp 2x.
        f32x4 uaA = uaC, uaB = {0.f, 0.f, 0.f, 0.f};
        f32x4 dhA = {0.f, 0.f, 0.f, 0.f};
        f32x4 dhB = {0.f, 0.f, 0.f, 0.f};
        f32x4 dhC = {0.f, 0.f, 0.f, 0.f};
        float hp0 = 0.f, hp1 = 0.f;
        #pragma unroll 2
        for (int c = 0; c < 8; ++c) {
            // ---- low-precision chain: z1 -> tanh -> ua (O(1) sensitivity)
            f32x4 b1 = *(const f32x4*)(&bc1_s[c*16 + q*4]);
            f32x4 z1 = mm(az1_s[c*64 + lane], bsh, b1);
            half4 t1h = toh(tanh4(z1));
            if (c & 1) uaB = mm(aua_s[c*64 + lane], t1h, uaB);
            else       uaA = mm(aua_s[c*64 + lane], t1h, uaA);

            // ---- high-precision chain: z2 (split x split, 3 MFMAs)
            f32x4 b2v = *(const f32x4*)(&bh1_s[c*16 + q*4]);
            half4 a2h = az2h_s[c*64 + lane];
            f32x4 z2 = mm(a2h, bsl, b2v);
            z2 = mm(az2l_s[c*64 + lane], bsh, z2);
            z2 = mm(a2h, bsh, z2);
            f32x4 t2 = tanh4(z2);
            f32x4 s2;
            s2.x = 1.f - t2.x*t2.x; s2.y = 1.f - t2.y*t2.y;
            s2.z = 1.f - t2.z*t2.z; s2.w = 1.f - t2.w*t2.w;
            half4 s2h, s2l;
            split4(s2, s2h, s2l);
            half4 adh_h = adhh_s[c*64 + lane];
            dhA = mm(adh_h, s2h, dhA);
            dhB = mm(adhl_s[c*64 + lane], s2h, dhB);
            dhC = mm(adh_h, s2l, dhC);

            f32x4 wv = *(const f32x4*)(&wh2_s[c*16 + q*4]);
            if (c & 1) hp1 += dot4(wv, t2);
            else       hp0 += dot4(wv, t2);
        }
        f32x4 ua = uaA + uaB;
        f32x4 dh = dhA + dhB + dhC;
        float hp = hp0 + hp1;

        // f^T (rows = s) and G chunks (chunk a: row s = g[s][a]) — split path
        half4 fh = afh_s[lane], fl = afl_s[lane];
        f32x4 fD = mm(fh, bsl, bfC);
        fD = mm(fl, bsh, fD);
        fD = mm(fh, bsh, fD);
        f32x4 G0, G1, G2, G3;
        {
            half4 gh = agh_s[0*64 + lane], gl = agl_s[0*64 + lane];
            G0 = mm(gh, bsl, bgC0); G0 = mm(gl, bsh, G0); G0 = mm(gh, bsh, G0);
        }
        {
            half4 gh = agh_s[1*64 + lane], gl = agl_s[1*64 + lane];
            G1 = mm(gh, bsl, bgC1); G1 = mm(gl, bsh, G1); G1 = mm(gh, bsh, G1);
        }
        {
            half4 gh = agh_s[2*64 + lane], gl = agl_s[2*64 + lane];
            G2 = mm(gh, bsl, bgC2); G2 = mm(gl, bsh, G2); G2 = mm(gh, bsh, G2);
        }
        {
            half4 gh = agh_s[3*64 + lane], gl = agl_s[3*64 + lane];
            G3 = mm(gh, bsl, bgC3); G3 = mm(gl, bsh, G3); G3 = mm(gh, bsh, G3);
        }

        // right = h + bh2 + dh.f   (partials live in lane-quads; reduce)
        float right = redq(hp + dot4(dh, fD)) + bh2v;
        float l0 = -redq(dot4(dh, G0));
        float l1 = -redq(dot4(dh, G1));
        float l2 = -redq(dot4(dh, G2));
        float l3 = -redq(dot4(dh, G3));
        // ua rows >= 4 are zero, so quad-reduce == broadcast of rows 0-3
        float u0 = 2.f * redq(ua.x);
        float u1 = 2.f * redq(ua.y);
        float u2 = 2.f * redq(ua.z);
        float u3 = 2.f * redq(ua.w);

        float viol = l0*u0 + l1*u1 + l2*u2 + l3*u3 - right;
        float lsq  = l0*l0 + l1*l1 + l2*l2 + l3*l3;
        float lam  = viol > 0.f ? viol / (lsq + 1e-8f) : 0.f;

        if (q == 0) {                      // lanes 0-15 store their token
            f32x4 uo;
            uo.x = u0 - lam*l0; uo.y = u1 - lam*l1;
            uo.z = u2 - lam*l2; uo.w = u3 - lam*l3;
            *(f32x4*)(out + (size_t)(tile*16 + n) * ADIM) = uo;
        }
    }
}

extern "C" void kernel_launch(void* const* d_in, const int* in_sizes, int n_in,
                              void* d_out, int out_size, void* d_ws, size_t ws_size,
                              hipStream_t stream) {
    (void)in_sizes; (void)n_in; (void)d_ws; (void)ws_size; (void)out_size;
    const float* state = (const float*)d_in[0];
    const float* Wc1   = (const float*)d_in[1];
    const float* bc1   = (const float*)d_in[2];
    const float* Wc2   = (const float*)d_in[3];
    const float* bc2   = (const float*)d_in[4];
    const float* Wh1   = (const float*)d_in[5];
    const float* bh1   = (const float*)d_in[6];
    const float* wh2   = (const float*)d_in[7];
    const float* bh2   = (const float*)d_in[8];
    const float* Wf    = (const float*)d_in[9];
    const float* bf    = (const float*)d_in[10];
    const float* Wg    = (const float*)d_in[11];
    const float* bg    = (const float*)d_in[12];
    float* out = (float*)d_out;

    hipLaunchKernelGGL(cbf_qp_kernel, dim3(NBLK), dim3(256), 0, stream,
                       state, Wc1, bc1, Wc2, bc2, Wh1, bh1, wh2, bh2,
                       Wf, bf, Wg, bg, out);
}